// Round 1
// baseline (15801.312 us; speedup 1.0000x reference)
//
#include <hip/hip_runtime.h>
#include <math.h>

// ---------------------------------------------------------------------------
// PointerNetwork: biLSTM encoder + sequential pointer decoder (all fp32).
// Phase layout:
//   G1/G2: xWf/xWb = x@enc_Wih_{f,b} + b           (parallel GEMM)
//   G4/G3: b12 = x@W2 ; b3 = x@W3                  (parallel GEMM)
//   E:     lstm_seq (64 blocks = 2 dirs x 32 unit-groups, LDS-resident Whh
//          slices, per-step device-scope barrier) -> hn, hb
//   G5:    decIn = gate(t>0)*concat(x[t-1],hn[t-1])@dec_Wih + dec_b
//   G6:    b12 += concat(hn,hb)@W1
//   D:     lstm_seq decoder (32 blocks) -> decH (h0=0, c0=hn[:,1023,:])
//   K:     decide kernel: ragged argmax chain per batch (off critical path)
// ---------------------------------------------------------------------------

__device__ __forceinline__ float sigf(float x) { return 1.0f / (1.0f + expf(-x)); }

// ---------------- GEMM: C[M,N] = gather(A)[M,K] @ B[K,N] (+bias) (+accum) ---
// SRC 0: A plain [M,K]
// SRC 1: row r=(b<<10)|t: t==0 -> 0 else concat(x[b][t-1], hn[b][t-1]); K=512
// SRC 2: row r: concat(hn[r], hb[r]); K=512
template<int SRC>
__global__ __launch_bounds__(256)
void gemm_k(const float* __restrict__ A, const float* __restrict__ A2,
            const float* __restrict__ B, const float* __restrict__ bias,
            float* __restrict__ C, int M, int N, int K, int accum)
{
  __shared__ float As[16][68];   // [kk][m], pad 68 keeps 16B row alignment (272B)
  __shared__ float Bs[16][64];   // [kk][n]
  const int tid = threadIdx.x;
  const int m0 = blockIdx.y * 64;
  const int n0 = blockIdx.x * 64;
  const int am = tid >> 2, akq = tid & 3;    // A loader: row am, k-quad akq
  const int bkk = tid >> 4, bnq = tid & 15;  // B loader
  const int tx = tid & 15, ty = tid >> 4;    // micro-tile coords
  float acc[4][4] = {};
  for (int k0 = 0; k0 < K; k0 += 16) {
    float4 av;
    const int ar = m0 + am;
    const int ak = k0 + 4 * akq;
    if (SRC == 0) {
      av = *(const float4*)&A[ar * K + ak];
    } else if (SRC == 1) {
      const int bb = ar >> 10, t = ar & 1023;
      if (t == 0) { av = make_float4(0.f, 0.f, 0.f, 0.f); }
      else {
        const int src = ((bb << 10) + (t - 1)) * 256;
        av = (ak < 256) ? *(const float4*)&A[src + ak]
                        : *(const float4*)&A2[src + (ak - 256)];
      }
    } else {
      const int src = ar * 256;
      av = (ak < 256) ? *(const float4*)&A[src + ak]
                      : *(const float4*)&A2[src + (ak - 256)];
    }
    const float4 bv = *(const float4*)&B[(k0 + bkk) * N + n0 + 4 * bnq];
    As[4 * akq + 0][am] = av.x;
    As[4 * akq + 1][am] = av.y;
    As[4 * akq + 2][am] = av.z;
    As[4 * akq + 3][am] = av.w;
    *(float4*)&Bs[bkk][4 * bnq] = bv;
    __syncthreads();
#pragma unroll
    for (int kk = 0; kk < 16; ++kk) {
      const float4 a = *(const float4*)&As[kk][4 * ty];
      const float4 b = *(const float4*)&Bs[kk][4 * tx];
      acc[0][0] += a.x * b.x; acc[0][1] += a.x * b.y; acc[0][2] += a.x * b.z; acc[0][3] += a.x * b.w;
      acc[1][0] += a.y * b.x; acc[1][1] += a.y * b.y; acc[1][2] += a.y * b.z; acc[1][3] += a.y * b.w;
      acc[2][0] += a.z * b.x; acc[2][1] += a.z * b.y; acc[2][2] += a.z * b.z; acc[2][3] += a.z * b.w;
      acc[3][0] += a.w * b.x; acc[3][1] += a.w * b.y; acc[3][2] += a.w * b.z; acc[3][3] += a.w * b.w;
    }
    __syncthreads();
  }
  const float4 bsv = bias ? *(const float4*)&bias[n0 + 4 * tx] : make_float4(0.f, 0.f, 0.f, 0.f);
#pragma unroll
  for (int i = 0; i < 4; ++i) {
    float* crow = &C[(m0 + 4 * ty + i) * N + n0 + 4 * tx];
    float4 old = accum ? *(const float4*)crow : make_float4(0.f, 0.f, 0.f, 0.f);
    float4 r;
    r.x = acc[i][0] + old.x + bsv.x;
    r.y = acc[i][1] + old.y + bsv.y;
    r.z = acc[i][2] + old.z + bsv.z;
    r.w = acc[i][3] + old.w + bsv.w;
    *(float4*)crow = r;
  }
}

// ---------------- Sequential LSTM (unit-split across blocks) ----------------
// Grid = ndirs*groups blocks of 512 threads. Block (dir,g) owns 8 hidden units
// (32 gate-columns); its Whh slice lives in LDS (transposed, padded). Per step:
// all threads dot h (LDS) with their column, combine gates per unit, write h2
// to global, device-scope barrier, re-gather full h from global.
__global__ __launch_bounds__(512)
void lstm_seq(const float* __restrict__ xW0, const float* __restrict__ xW1,
              const float* __restrict__ Wr0, const float* __restrict__ Wr1,
              float* __restrict__ hout0, float* __restrict__ hout1,
              const float* __restrict__ cinit,
              unsigned* __restrict__ ctr, int groups, int rev1)
{
  const int dir = blockIdx.x / groups;
  const int g   = blockIdx.x % groups;
  const float* xW = dir ? xW1 : xW0;
  const float* Wr = dir ? Wr1 : Wr0;
  float* hout     = dir ? hout1 : hout0;
  unsigned* cc    = ctr + dir * 1024;

  const int tid  = threadIdx.x;
  const int b    = tid & 15;     // batch
  const int sc   = tid >> 4;     // slice column 0..31
  const int gate = sc & 3;       // 0=i 1=f 2=g 3=o  (jnp.split order)
  const int uu   = sc >> 2;      // unit-in-block 0..7
  const int col  = gate * 256 + g * 8 + uu;   // global gate-column
  const int u    = g * 8 + uu;                // global hidden unit
  const bool is_c = (gate == 0);

  __shared__ float wT[32][260];   // wT[sc][k] = Whh[k][col], pad 260 -> no conflicts
  __shared__ float hbuf[16][260]; // [b][k]
  __shared__ float zbuf[16][36];  // [b][sc], pad 36 (144B rows, 16B aligned)

  for (int i = 0; i < 16; ++i) {
    const int k = b * 16 + i;
    wT[sc][k] = Wr[k * 1024 + col];
  }
  for (int i = 0; i < 8; ++i) hbuf[b][sc * 8 + i] = 0.0f;

  float creg = 0.0f;
  if (cinit && is_c) creg = cinit[((b << 10) + 1023) * 256 + u];
  __syncthreads();

  int tprev = 0;
  for (int s = 0; s < 1024; ++s) {
    const int t = (dir & rev1) ? (1023 - s) : s;
    const float xwv = xW[((b << 10) + t) * 1024 + col];  // prefetched, used late
    if (s > 0) {
      const float4 h0 = *(const float4*)&hout[((b << 10) + tprev) * 256 + sc * 8];
      const float4 h1 = *(const float4*)&hout[((b << 10) + tprev) * 256 + sc * 8 + 4];
      *(float4*)&hbuf[b][sc * 8]     = h0;
      *(float4*)&hbuf[b][sc * 8 + 4] = h1;
    }
    __syncthreads();
    float a0 = 0.f, a1 = 0.f, a2 = 0.f, a3 = 0.f;
    const float* wrow = &wT[sc][0];
    const float* hrow = &hbuf[b][0];
#pragma unroll 8
    for (int k = 0; k < 256; k += 4) {
      const float4 w = *(const float4*)&wrow[k];
      const float4 h = *(const float4*)&hrow[k];
      a0 += w.x * h.x; a1 += w.y * h.y; a2 += w.z * h.z; a3 += w.w * h.w;
    }
    zbuf[b][sc] = (a0 + a1) + (a2 + a3) + xwv;
    __syncthreads();
    if (is_c) {
      const float zi = zbuf[b][4 * uu + 0];
      const float zf = zbuf[b][4 * uu + 1];
      const float zg = zbuf[b][4 * uu + 2];
      const float zo = zbuf[b][4 * uu + 3];
      const float c2 = sigf(zf) * creg + sigf(zi) * tanhf(zg);
      const float h2 = sigf(zo) * tanhf(c2);
      creg = c2;
      hout[((b << 10) + t) * 256 + u] = h2;
    }
    __syncthreads();
    if (tid == 0) {
      __hip_atomic_fetch_add(&cc[s], 1u, __ATOMIC_RELEASE, __HIP_MEMORY_SCOPE_AGENT);
      long spin = 0;
      while (__hip_atomic_load(&cc[s], __ATOMIC_ACQUIRE, __HIP_MEMORY_SCOPE_AGENT)
             < (unsigned)groups) {
        __builtin_amdgcn_s_sleep(1);
        if (++spin > (1L << 20)) break;  // failsafe: wrong-but-terminating > hang
      }
    }
    __syncthreads();
    tprev = t;
  }
}

// ---------------- Decision pass (off the sequential critical path) ----------
// One block per batch. Walks the decision chain t -> argmax_{j>=t}(score_j+out2).
__global__ __launch_bounds__(256)
void decide_k(const float* __restrict__ decH, const float* __restrict__ b12,
              const float* __restrict__ b3, const float* __restrict__ W4,
              const float* __restrict__ vt1, const float* __restrict__ vt2,
              const float* __restrict__ cemb, float* __restrict__ out)
{
  const int b = blockIdx.x, tid = threadIdx.x;
  __shared__ float v1s[256], add3[256], hrow[256], redv[256];
  __shared__ int   redi[256];
  __shared__ float s_out2;
  __shared__ int   s_r;
  v1s[tid] = vt1[tid];
  int bond = 0, last = 0;
  for (int iter = 0; iter < 1024; ++iter) {
    const int t = bond;
    hrow[tid] = decH[((b << 10) + t) * 256 + tid];
    redv[tid] = cemb[(t - last) * 256 + tid] * vt2[tid];
    __syncthreads();
    for (int off = 128; off; off >>= 1) {
      if (tid < off) redv[tid] += redv[tid + off];
      __syncthreads();
    }
    if (tid == 0) s_out2 = redv[0];
    __syncthreads();
    float a = 0.f;
#pragma unroll 4
    for (int k = 0; k < 256; ++k) a += hrow[k] * W4[k * 256 + tid];
    add3[tid] = a + b3[((b << 10) + t) * 256 + tid];
    __syncthreads();
    const float out2 = s_out2;
    float best = -INFINITY; int bestj = 0x7fffffff;
    for (int j = t + tid; j < 1024; j += 256) {
      const float* row = &b12[((b << 10) + j) * 256];
      float sacc = 0.f;
      for (int n = 0; n < 256; n += 4) {
        const float4 rv = *(const float4*)&row[n];
        sacc += tanhf(rv.x + add3[n + 0]) * v1s[n + 0];
        sacc += tanhf(rv.y + add3[n + 1]) * v1s[n + 1];
        sacc += tanhf(rv.z + add3[n + 2]) * v1s[n + 2];
        sacc += tanhf(rv.w + add3[n + 3]) * v1s[n + 3];
      }
      const float logit = sacc + out2;
      if (logit > best || (logit == best && j < bestj)) { best = logit; bestj = j; }
    }
    redv[tid] = best; redi[tid] = bestj;
    __syncthreads();
    for (int off = 128; off; off >>= 1) {
      if (tid < off) {
        const float v2 = redv[tid + off]; const int j2 = redi[tid + off];
        if (v2 > redv[tid] || (v2 == redv[tid] && j2 < redi[tid])) {
          redv[tid] = v2; redi[tid] = j2;
        }
      }
      __syncthreads();
    }
    if (tid == 0) { s_r = redi[0]; out[redi[0] * 16 + b] = 1.0f; }
    __syncthreads();
    const int r = s_r;
    if (r == t) break;       // bond stuck -> no future decision step
    last = t; bond = r;
    __syncthreads();         // protect shared reuse
  }
}

// ---------------------------------------------------------------------------
extern "C" void kernel_launch(void* const* d_in, const int* in_sizes, int n_in,
                              void* d_out, int out_size, void* d_ws, size_t ws_size,
                              hipStream_t stream)
{
  const float* x     = (const float*)d_in[0];
  const float* Wih_f = (const float*)d_in[1];
  const float* Whh_f = (const float*)d_in[2];
  const float* b_f   = (const float*)d_in[3];
  const float* Wih_b = (const float*)d_in[4];
  const float* Whh_b = (const float*)d_in[5];
  const float* b_b   = (const float*)d_in[6];
  const float* dWih  = (const float*)d_in[7];
  const float* dWhh  = (const float*)d_in[8];
  const float* db    = (const float*)d_in[9];
  const float* W1    = (const float*)d_in[10];
  const float* W2    = (const float*)d_in[11];
  const float* W3    = (const float*)d_in[12];
  const float* W4    = (const float*)d_in[13];
  const float* vt1   = (const float*)d_in[14];
  const float* vt2   = (const float*)d_in[15];
  const float* cemb  = (const float*)d_in[16];
  float* out = (float*)d_out;

  char* ws = (char*)d_ws;
  float*    xWf   = (float*)(ws);                          // 64 MB (reused as decIn)
  float*    xWb   = (float*)(ws + (size_t)(64u << 20));    // 64 MB (reused as decH)
  float*    hn    = (float*)(ws + (size_t)(128u << 20));   // 16 MB
  float*    hb    = (float*)(ws + (size_t)(144u << 20));   // 16 MB
  float*    b12   = (float*)(ws + (size_t)(160u << 20));   // 16 MB
  float*    b3    = (float*)(ws + (size_t)(176u << 20));   // 16 MB
  unsigned* ctr   = (unsigned*)(ws + (size_t)(192u << 20)); // 12 KB barrier ctrs
  float* decIn = xWf;   // xWf dead after encoder
  float* decH  = xWb;   // xWb dead after encoder

  hipMemsetAsync(ctr, 0, 3 * 1024 * sizeof(unsigned), stream);
  hipMemsetAsync(out, 0, (size_t)out_size * sizeof(float), stream);

  const dim3 blk(256);
  // Pre-encoder GEMMs
  gemm_k<0><<<dim3(16, 256), blk, 0, stream>>>(x, nullptr, Wih_f, b_f, xWf, 16384, 1024, 256, 0);
  gemm_k<0><<<dim3(16, 256), blk, 0, stream>>>(x, nullptr, Wih_b, b_b, xWb, 16384, 1024, 256, 0);
  gemm_k<0><<<dim3(4, 256),  blk, 0, stream>>>(x, nullptr, W2, nullptr, b12, 16384, 256, 256, 0);
  gemm_k<0><<<dim3(4, 256),  blk, 0, stream>>>(x, nullptr, W3, nullptr, b3,  16384, 256, 256, 0);
  // Encoder: 2 dirs x 32 groups
  lstm_seq<<<64, 512, 0, stream>>>(xWf, xWb, Whh_f, Whh_b, hn, hb, nullptr, ctr, 32, 1);
  // Post-encoder GEMMs
  gemm_k<1><<<dim3(16, 256), blk, 0, stream>>>(x, hn, dWih, db, decIn, 16384, 1024, 512, 0);
  gemm_k<2><<<dim3(4, 256),  blk, 0, stream>>>(hn, hb, W1, nullptr, b12, 16384, 256, 512, 1);
  // Decoder: 32 groups, c0 = hn[:,1023,:]
  lstm_seq<<<32, 512, 0, stream>>>(decIn, nullptr, dWhh, nullptr, decH, nullptr, hn, ctr + 2048, 32, 0);
  // Decision chain
  decide_k<<<16, 256, 0, stream>>>(decH, b12, b3, W4, vt1, vt2, cemb, out);
}

// Round 2
// 15397.868 us; speedup vs baseline: 1.0262x; 1.0262x over previous
//
#include <hip/hip_runtime.h>
#include <math.h>

// ---------------------------------------------------------------------------
// PointerNetwork: biLSTM encoder + sequential pointer decoder (all fp32).
//   G1/G2: xWf/xWb = x@enc_Wih_{f,b} + b           (parallel GEMM)
//   G4/G3: b12 = x@W2 ; b3 = x@W3                  (parallel GEMM)
//   E:     lstm_seq (64 blocks = 2 dirs x 32 unit-groups) -> hn, hb
//          Whh slice in REGISTERS; h exchanged via agent-scope relaxed
//          atomics (L2-bypass reads, write-through stores) so the per-step
//          barrier never invalidates L2 (xW stays cached).
//   G5:    decIn = gate(t>0)*concat(x[t-1],hn[t-1])@dec_Wih + dec_b
//   G6:    b12 += concat(hn,hb)@W1
//   D:     lstm_seq decoder (32 blocks) -> decH (h0=0, c0=hn[:,1023,:])
//   K:     decide kernel: ragged argmax chain per batch
// ---------------------------------------------------------------------------

__device__ __forceinline__ float sigf(float x) { return 1.0f / (1.0f + expf(-x)); }

// ---------------- GEMM: C[M,N] = gather(A)[M,K] @ B[K,N] (+bias) (+accum) ---
template<int SRC>
__global__ __launch_bounds__(256)
void gemm_k(const float* __restrict__ A, const float* __restrict__ A2,
            const float* __restrict__ B, const float* __restrict__ bias,
            float* __restrict__ C, int M, int N, int K, int accum)
{
  __shared__ float As[16][68];
  __shared__ float Bs[16][64];
  const int tid = threadIdx.x;
  const int m0 = blockIdx.y * 64;
  const int n0 = blockIdx.x * 64;
  const int am = tid >> 2, akq = tid & 3;
  const int bkk = tid >> 4, bnq = tid & 15;
  const int tx = tid & 15, ty = tid >> 4;
  float acc[4][4] = {};
  for (int k0 = 0; k0 < K; k0 += 16) {
    float4 av;
    const int ar = m0 + am;
    const int ak = k0 + 4 * akq;
    if (SRC == 0) {
      av = *(const float4*)&A[ar * K + ak];
    } else if (SRC == 1) {
      const int bb = ar >> 10, t = ar & 1023;
      if (t == 0) { av = make_float4(0.f, 0.f, 0.f, 0.f); }
      else {
        const int src = ((bb << 10) + (t - 1)) * 256;
        av = (ak < 256) ? *(const float4*)&A[src + ak]
                        : *(const float4*)&A2[src + (ak - 256)];
      }
    } else {
      const int src = ar * 256;
      av = (ak < 256) ? *(const float4*)&A[src + ak]
                      : *(const float4*)&A2[src + (ak - 256)];
    }
    const float4 bv = *(const float4*)&B[(k0 + bkk) * N + n0 + 4 * bnq];
    As[4 * akq + 0][am] = av.x;
    As[4 * akq + 1][am] = av.y;
    As[4 * akq + 2][am] = av.z;
    As[4 * akq + 3][am] = av.w;
    *(float4*)&Bs[bkk][4 * bnq] = bv;
    __syncthreads();
#pragma unroll
    for (int kk = 0; kk < 16; ++kk) {
      const float4 a = *(const float4*)&As[kk][4 * ty];
      const float4 b = *(const float4*)&Bs[kk][4 * tx];
      acc[0][0] += a.x * b.x; acc[0][1] += a.x * b.y; acc[0][2] += a.x * b.z; acc[0][3] += a.x * b.w;
      acc[1][0] += a.y * b.x; acc[1][1] += a.y * b.y; acc[1][2] += a.y * b.z; acc[1][3] += a.y * b.w;
      acc[2][0] += a.z * b.x; acc[2][1] += a.z * b.y; acc[2][2] += a.z * b.z; acc[2][3] += a.z * b.w;
      acc[3][0] += a.w * b.x; acc[3][1] += a.w * b.y; acc[3][2] += a.w * b.z; acc[3][3] += a.w * b.w;
    }
    __syncthreads();
  }
  const float4 bsv = bias ? *(const float4*)&bias[n0 + 4 * tx] : make_float4(0.f, 0.f, 0.f, 0.f);
#pragma unroll
  for (int i = 0; i < 4; ++i) {
    float* crow = &C[(m0 + 4 * ty + i) * N + n0 + 4 * tx];
    float4 old = accum ? *(const float4*)crow : make_float4(0.f, 0.f, 0.f, 0.f);
    float4 r;
    r.x = acc[i][0] + old.x + bsv.x;
    r.y = acc[i][1] + old.y + bsv.y;
    r.z = acc[i][2] + old.z + bsv.z;
    r.w = acc[i][3] + old.w + bsv.w;
    *(float4*)crow = r;
  }
}

// ---------------- Sequential LSTM (unit-split, register-resident weights) ---
// 512 threads/block. Compute role: tid = cg*64 + bg*8 + kc.
//   cg in [0,8): owns 4 gate-cols (local c = 4cg+j, j = gate)
//   kc in [0,8): k-chunk, STRIDED float4 groups g4 = kc + 8m (bank spread)
//   bg in [0,8): 2 batches (2bg, 2bg+1)
// Weights wf[4][8] (float4) = 128 VGPRs per thread, loaded once.
// Output role: tid = sc*16 + b; sc=4*uu+gate; z combine + activation by gate0.
__global__ __launch_bounds__(512, 2)
void lstm_seq(const float* __restrict__ xW0, const float* __restrict__ xW1,
              const float* __restrict__ Wr0, const float* __restrict__ Wr1,
              float* __restrict__ hout0, float* __restrict__ hout1,
              const float* __restrict__ cinit,
              unsigned* __restrict__ ctr, int groups, int rev1)
{
  const int dir = blockIdx.x / groups;
  const int g   = blockIdx.x % groups;
  const float* xW = dir ? xW1 : xW0;
  const float* Wr = dir ? Wr1 : Wr0;
  float* hout     = dir ? hout1 : hout0;
  unsigned* cc    = ctr + dir * 1024;

  const int tid = threadIdx.x;
  // compute role
  const int kc = tid & 7;
  const int bg = (tid >> 3) & 7;
  const int cg = tid >> 6;
  // output role
  const int b    = tid & 15;
  const int sc   = tid >> 4;          // local col 0..31
  const int gate = sc & 3;
  const int uu   = sc >> 2;
  const int ocol = gate * 256 + g * 8 + uu;   // global gate-column
  const int u    = g * 8 + uu;                // global hidden unit
  const bool is_c = (gate == 0);

  __shared__ float hbuf[16 * 260];   // h[b][k], row stride 260
  __shared__ float pbuf[16 * 260];   // partials [b][c*8+kc], row stride 260
  __shared__ float zbuf[16][36];     // z[b][sc]

  // Load register weight tile: col (j<<8)+g*8+cg, k groups kc+8m.
  float4 wf[4][8];
#pragma unroll
  for (int j = 0; j < 4; ++j) {
    const int col = (j << 8) + g * 8 + cg;
#pragma unroll
    for (int m = 0; m < 8; ++m) {
      const int k0 = 4 * (kc + 8 * m);
      wf[j][m].x = Wr[(k0 + 0) * 1024 + col];
      wf[j][m].y = Wr[(k0 + 1) * 1024 + col];
      wf[j][m].z = Wr[(k0 + 2) * 1024 + col];
      wf[j][m].w = Wr[(k0 + 3) * 1024 + col];
    }
  }
#pragma unroll
  for (int e = 0; e < 8; ++e) hbuf[b * 260 + 8 * sc + e] = 0.0f;

  float creg = 0.0f;
  if (cinit && is_c) creg = cinit[((b << 10) + 1023) * 256 + u];
  __syncthreads();

  int tprev = 0;
  for (int s = 0; s < 1024; ++s) {
    const int t = (dir & rev1) ? (1023 - s) : s;
    const float xwv = xW[((b << 10) + t) * 1024 + ocol];  // L2-cached (no invalidates!)
    if (s > 0) {
      // Coherent read-back of h[t-1] (bypasses stale L1/L2).
      const float* src = &hout[((b << 10) + tprev) * 256 + 8 * sc];
      float4 t0, t1;
      t0.x = __hip_atomic_load(&src[0], __ATOMIC_RELAXED, __HIP_MEMORY_SCOPE_AGENT);
      t0.y = __hip_atomic_load(&src[1], __ATOMIC_RELAXED, __HIP_MEMORY_SCOPE_AGENT);
      t0.z = __hip_atomic_load(&src[2], __ATOMIC_RELAXED, __HIP_MEMORY_SCOPE_AGENT);
      t0.w = __hip_atomic_load(&src[3], __ATOMIC_RELAXED, __HIP_MEMORY_SCOPE_AGENT);
      t1.x = __hip_atomic_load(&src[4], __ATOMIC_RELAXED, __HIP_MEMORY_SCOPE_AGENT);
      t1.y = __hip_atomic_load(&src[5], __ATOMIC_RELAXED, __HIP_MEMORY_SCOPE_AGENT);
      t1.z = __hip_atomic_load(&src[6], __ATOMIC_RELAXED, __HIP_MEMORY_SCOPE_AGENT);
      t1.w = __hip_atomic_load(&src[7], __ATOMIC_RELAXED, __HIP_MEMORY_SCOPE_AGENT);
      *(float4*)&hbuf[b * 260 + 8 * sc]     = t0;
      *(float4*)&hbuf[b * 260 + 8 * sc + 4] = t1;
    }
    __syncthreads();

    // MAC: pj[i][j] = sum over this thread's 32 k of h[2bg+i][k]*Whh[k][4cg+j]
    float pj[2][4] = {};
#pragma unroll
    for (int i = 0; i < 2; ++i) {
      const float* hrow = &hbuf[(2 * bg + i) * 260];
#pragma unroll
      for (int m = 0; m < 8; ++m) {
        const float4 hv = *(const float4*)&hrow[4 * (kc + 8 * m)];
#pragma unroll
        for (int j = 0; j < 4; ++j) {
          pj[i][j] += hv.x * wf[j][m].x;
          pj[i][j] += hv.y * wf[j][m].y;
          pj[i][j] += hv.z * wf[j][m].z;
          pj[i][j] += hv.w * wf[j][m].w;
        }
      }
    }
#pragma unroll
    for (int i = 0; i < 2; ++i)
#pragma unroll
      for (int j = 0; j < 4; ++j)
        pbuf[(2 * bg + i) * 260 + (4 * cg + j) * 8 + kc] = pj[i][j];
    __syncthreads();

    // k-split reduction + xW add (output role)
    const float4 p0 = *(const float4*)&pbuf[b * 260 + 8 * sc];
    const float4 p1 = *(const float4*)&pbuf[b * 260 + 8 * sc + 4];
    zbuf[b][sc] = xwv + (((p0.x + p0.y) + (p0.z + p0.w)) +
                         ((p1.x + p1.y) + (p1.z + p1.w)));
    __syncthreads();

    if (is_c) {
      const float zi = zbuf[b][sc + 0];
      const float zf = zbuf[b][sc + 1];
      const float zg = zbuf[b][sc + 2];
      const float zo = zbuf[b][sc + 3];
      const float c2 = sigf(zf) * creg + sigf(zi) * tanhf(zg);
      const float h2 = sigf(zo) * tanhf(c2);
      creg = c2;
      // Write-through store (agent scope): visible at coherence point, L2 clean.
      __hip_atomic_store(&hout[((b << 10) + t) * 256 + u], h2,
                         __ATOMIC_RELAXED, __HIP_MEMORY_SCOPE_AGENT);
    }

    if (s < 1023) {
      // Every wave drains its own h-stores before the block signals arrival.
      asm volatile("s_waitcnt vmcnt(0)" ::: "memory");
      __syncthreads();
      if (tid == 0) {
        __hip_atomic_fetch_add(&cc[s], 1u, __ATOMIC_RELEASE, __HIP_MEMORY_SCOPE_AGENT);
        int spin = 0;
        while (__hip_atomic_load(&cc[s], __ATOMIC_RELAXED, __HIP_MEMORY_SCOPE_AGENT)
               < (unsigned)groups) {
          __builtin_amdgcn_s_sleep(1);
          if (++spin > (1 << 16)) break;  // failsafe: terminate > hang
        }
      }
      __syncthreads();
    }
    tprev = t;
  }
}

// ---------------- Decision pass (off the sequential critical path) ----------
__global__ __launch_bounds__(256)
void decide_k(const float* __restrict__ decH, const float* __restrict__ b12,
              const float* __restrict__ b3, const float* __restrict__ W4,
              const float* __restrict__ vt1, const float* __restrict__ vt2,
              const float* __restrict__ cemb, float* __restrict__ out)
{
  const int b = blockIdx.x, tid = threadIdx.x;
  __shared__ float v1s[256], add3[256], hrow[256], redv[256];
  __shared__ int   redi[256];
  __shared__ float s_out2;
  __shared__ int   s_r;
  v1s[tid] = vt1[tid];
  int bond = 0, last = 0;
  for (int iter = 0; iter < 1024; ++iter) {
    const int t = bond;
    hrow[tid] = decH[((b << 10) + t) * 256 + tid];
    redv[tid] = cemb[(t - last) * 256 + tid] * vt2[tid];
    __syncthreads();
    for (int off = 128; off; off >>= 1) {
      if (tid < off) redv[tid] += redv[tid + off];
      __syncthreads();
    }
    if (tid == 0) s_out2 = redv[0];
    __syncthreads();
    float a = 0.f;
#pragma unroll 4
    for (int k = 0; k < 256; ++k) a += hrow[k] * W4[k * 256 + tid];
    add3[tid] = a + b3[((b << 10) + t) * 256 + tid];
    __syncthreads();
    const float out2 = s_out2;
    float best = -INFINITY; int bestj = 0x7fffffff;
    for (int j = t + tid; j < 1024; j += 256) {
      const float* row = &b12[((b << 10) + j) * 256];
      float sacc = 0.f;
      for (int n = 0; n < 256; n += 4) {
        const float4 rv = *(const float4*)&row[n];
        sacc += tanhf(rv.x + add3[n + 0]) * v1s[n + 0];
        sacc += tanhf(rv.y + add3[n + 1]) * v1s[n + 1];
        sacc += tanhf(rv.z + add3[n + 2]) * v1s[n + 2];
        sacc += tanhf(rv.w + add3[n + 3]) * v1s[n + 3];
      }
      const float logit = sacc + out2;
      if (logit > best || (logit == best && j < bestj)) { best = logit; bestj = j; }
    }
    redv[tid] = best; redi[tid] = bestj;
    __syncthreads();
    for (int off = 128; off; off >>= 1) {
      if (tid < off) {
        const float v2 = redv[tid + off]; const int j2 = redi[tid + off];
        if (v2 > redv[tid] || (v2 == redv[tid] && j2 < redi[tid])) {
          redv[tid] = v2; redi[tid] = j2;
        }
      }
      __syncthreads();
    }
    if (tid == 0) { s_r = redi[0]; out[redi[0] * 16 + b] = 1.0f; }
    __syncthreads();
    const int r = s_r;
    if (r == t) break;
    last = t; bond = r;
    __syncthreads();
  }
}

// ---------------------------------------------------------------------------
extern "C" void kernel_launch(void* const* d_in, const int* in_sizes, int n_in,
                              void* d_out, int out_size, void* d_ws, size_t ws_size,
                              hipStream_t stream)
{
  const float* x     = (const float*)d_in[0];
  const float* Wih_f = (const float*)d_in[1];
  const float* Whh_f = (const float*)d_in[2];
  const float* b_f   = (const float*)d_in[3];
  const float* Wih_b = (const float*)d_in[4];
  const float* Whh_b = (const float*)d_in[5];
  const float* b_b   = (const float*)d_in[6];
  const float* dWih  = (const float*)d_in[7];
  const float* dWhh  = (const float*)d_in[8];
  const float* db    = (const float*)d_in[9];
  const float* W1    = (const float*)d_in[10];
  const float* W2    = (const float*)d_in[11];
  const float* W3    = (const float*)d_in[12];
  const float* W4    = (const float*)d_in[13];
  const float* vt1   = (const float*)d_in[14];
  const float* vt2   = (const float*)d_in[15];
  const float* cemb  = (const float*)d_in[16];
  float* out = (float*)d_out;

  char* ws = (char*)d_ws;
  float*    xWf   = (float*)(ws);                           // 64 MB (reused as decIn)
  float*    xWb   = (float*)(ws + (size_t)(64u << 20));     // 64 MB (reused as decH)
  float*    hn    = (float*)(ws + (size_t)(128u << 20));    // 16 MB
  float*    hb    = (float*)(ws + (size_t)(144u << 20));    // 16 MB
  float*    b12   = (float*)(ws + (size_t)(160u << 20));    // 16 MB
  float*    b3    = (float*)(ws + (size_t)(176u << 20));    // 16 MB
  unsigned* ctr   = (unsigned*)(ws + (size_t)(192u << 20)); // 12 KB barrier ctrs
  float* decIn = xWf;
  float* decH  = xWb;

  hipMemsetAsync(ctr, 0, 3 * 1024 * sizeof(unsigned), stream);
  hipMemsetAsync(out, 0, (size_t)out_size * sizeof(float), stream);

  const dim3 blk(256);
  gemm_k<0><<<dim3(16, 256), blk, 0, stream>>>(x, nullptr, Wih_f, b_f, xWf, 16384, 1024, 256, 0);
  gemm_k<0><<<dim3(16, 256), blk, 0, stream>>>(x, nullptr, Wih_b, b_b, xWb, 16384, 1024, 256, 0);
  gemm_k<0><<<dim3(4, 256),  blk, 0, stream>>>(x, nullptr, W2, nullptr, b12, 16384, 256, 256, 0);
  gemm_k<0><<<dim3(4, 256),  blk, 0, stream>>>(x, nullptr, W3, nullptr, b3,  16384, 256, 256, 0);
  lstm_seq<<<64, 512, 0, stream>>>(xWf, xWb, Whh_f, Whh_b, hn, hb, nullptr, ctr, 32, 1);
  gemm_k<1><<<dim3(16, 256), blk, 0, stream>>>(x, hn, dWih, db, decIn, 16384, 1024, 512, 0);
  gemm_k<2><<<dim3(4, 256),  blk, 0, stream>>>(hn, hb, W1, nullptr, b12, 16384, 256, 512, 1);
  lstm_seq<<<32, 512, 0, stream>>>(decIn, nullptr, dWhh, nullptr, decH, nullptr, hn, ctr + 2048, 32, 0);
  decide_k<<<16, 256, 0, stream>>>(decH, b12, b3, W4, vt1, vt2, cemb, out);
}

// Round 3
// 8029.891 us; speedup vs baseline: 1.9678x; 1.9176x over previous
//
#include <hip/hip_runtime.h>
#include <math.h>

// ---------------------------------------------------------------------------
// PointerNetwork: biLSTM encoder + sequential pointer decoder (all fp32).
// Recurrences: 32 blocks/chain, Whh slices in VGPRs. Per-step sync via
// per-block FLAGS (64B-strided, no atomic contention) + a 4-slot full-line
// h exchange ring read/written with sc0|sc1 (coherence-point) accesses.
// ---------------------------------------------------------------------------

__device__ __forceinline__ float sigf(float x) { return 1.0f / (1.0f + expf(-x)); }

// ---------------- GEMM: C[M,N] = gather(A)[M,K] @ B[K,N] (+bias) (+accum) ---
template<int SRC>
__global__ __launch_bounds__(256)
void gemm_k(const float* __restrict__ A, const float* __restrict__ A2,
            const float* __restrict__ B, const float* __restrict__ bias,
            float* __restrict__ C, int M, int N, int K, int accum)
{
  __shared__ float As[16][68];
  __shared__ float Bs[16][64];
  const int tid = threadIdx.x;
  const int m0 = blockIdx.y * 64;
  const int n0 = blockIdx.x * 64;
  const int am = tid >> 2, akq = tid & 3;
  const int bkk = tid >> 4, bnq = tid & 15;
  const int tx = tid & 15, ty = tid >> 4;
  float acc[4][4] = {};
  for (int k0 = 0; k0 < K; k0 += 16) {
    float4 av;
    const int ar = m0 + am;
    const int ak = k0 + 4 * akq;
    if (SRC == 0) {
      av = *(const float4*)&A[ar * K + ak];
    } else if (SRC == 1) {
      const int bb = ar >> 10, t = ar & 1023;
      if (t == 0) { av = make_float4(0.f, 0.f, 0.f, 0.f); }
      else {
        const int src = ((bb << 10) + (t - 1)) * 256;
        av = (ak < 256) ? *(const float4*)&A[src + ak]
                        : *(const float4*)&A2[src + (ak - 256)];
      }
    } else {
      const int src = ar * 256;
      av = (ak < 256) ? *(const float4*)&A[src + ak]
                      : *(const float4*)&A2[src + (ak - 256)];
    }
    const float4 bv = *(const float4*)&B[(k0 + bkk) * N + n0 + 4 * bnq];
    As[4 * akq + 0][am] = av.x;
    As[4 * akq + 1][am] = av.y;
    As[4 * akq + 2][am] = av.z;
    As[4 * akq + 3][am] = av.w;
    *(float4*)&Bs[bkk][4 * bnq] = bv;
    __syncthreads();
#pragma unroll
    for (int kk = 0; kk < 16; ++kk) {
      const float4 a = *(const float4*)&As[kk][4 * ty];
      const float4 b = *(const float4*)&Bs[kk][4 * tx];
      acc[0][0] += a.x * b.x; acc[0][1] += a.x * b.y; acc[0][2] += a.x * b.z; acc[0][3] += a.x * b.w;
      acc[1][0] += a.y * b.x; acc[1][1] += a.y * b.y; acc[1][2] += a.y * b.z; acc[1][3] += a.y * b.w;
      acc[2][0] += a.z * b.x; acc[2][1] += a.z * b.y; acc[2][2] += a.z * b.z; acc[2][3] += a.z * b.w;
      acc[3][0] += a.w * b.x; acc[3][1] += a.w * b.y; acc[3][2] += a.w * b.z; acc[3][3] += a.w * b.w;
    }
    __syncthreads();
  }
  const float4 bsv = bias ? *(const float4*)&bias[n0 + 4 * tx] : make_float4(0.f, 0.f, 0.f, 0.f);
#pragma unroll
  for (int i = 0; i < 4; ++i) {
    float* crow = &C[(m0 + 4 * ty + i) * N + n0 + 4 * tx];
    float4 old = accum ? *(const float4*)crow : make_float4(0.f, 0.f, 0.f, 0.f);
    float4 r;
    r.x = acc[i][0] + old.x + bsv.x;
    r.y = acc[i][1] + old.y + bsv.y;
    r.z = acc[i][2] + old.z + bsv.z;
    r.w = acc[i][3] + old.w + bsv.w;
    *(float4*)crow = r;
  }
}

// ---------------- Sequential LSTM (flag sync + full-line exchange ring) -----
// 512 threads. Compute role tid = cg*64+bg*8+kc (cg = wave id, owns units
// g*8+cg across 4 gates; kc = strided k-chunk; bg = batch pair).
// Output role tid = sc*16+b; gate0 lanes (sc=4w) finalize unit u=g*8+w.
__global__ __launch_bounds__(512, 1)
void lstm_seq(const float* __restrict__ xW0, const float* __restrict__ xW1,
              const float* __restrict__ Wr0, const float* __restrict__ Wr1,
              float* __restrict__ hout0, float* __restrict__ hout1,
              const float* __restrict__ cinit,
              float* __restrict__ ring,      // [dir][4][4096] (u-major: u*16+b)
              unsigned* __restrict__ flags,  // [dir][32*16]
              int rev1)
{
  const int dir = blockIdx.x >> 5;
  const int g   = blockIdx.x & 31;
  const float* xW = dir ? xW1 : xW0;
  const float* Wr = dir ? Wr1 : Wr0;
  float* hout     = dir ? hout1 : hout0;
  float* rg       = ring + dir * 4 * 4096;
  unsigned* fl    = flags + dir * 512;

  const int tid  = threadIdx.x;
  const int lane = tid & 63;
  // compute role
  const int kc = tid & 7;
  const int bg = (tid >> 3) & 7;
  const int cg = tid >> 6;            // == wave id
  // output role
  const int b    = tid & 15;
  const int sc   = tid >> 4;
  const int gate = sc & 3;
  const int uu   = sc >> 2;           // == wave id for gate0 lanes
  const int u    = g * 8 + uu;
  const bool is_c = (gate == 0);

  __shared__ float hbuf[16 * 260];    // h[b][k]
  __shared__ float pbuf[16 * 260];    // partials [b][c*8+kc] (wave-private use)

  // Register weight tile: cols (j<<8)+g*8+cg, k groups kc+8m.
  float4 wf[4][8];
#pragma unroll
  for (int j = 0; j < 4; ++j) {
    const int col = (j << 8) + g * 8 + cg;
#pragma unroll
    for (int m = 0; m < 8; ++m) {
      const int k0 = 4 * (kc + 8 * m);
      wf[j][m].x = Wr[(k0 + 0) * 1024 + col];
      wf[j][m].y = Wr[(k0 + 1) * 1024 + col];
      wf[j][m].z = Wr[(k0 + 2) * 1024 + col];
      wf[j][m].w = Wr[(k0 + 3) * 1024 + col];
    }
  }
#pragma unroll
  for (int e = 0; e < 8; ++e) hbuf[b * 260 + 8 * sc + e] = 0.0f;

  float creg = 0.0f;
  if (cinit && is_c) creg = cinit[((b << 10) + 1023) * 256 + u];
  __syncthreads();

  for (int s = 0; s < 1024; ++s) {
    const int t = (dir & rev1) ? (1023 - s) : s;

    // Prefetch this step's xW (cached; consumed ~1us later).
    float xw4[4];
    if (is_c) {
      const int row = ((b << 10) + t) * 1024;
#pragma unroll
      for (int j = 0; j < 4; ++j) xw4[j] = xW[row + j * 256 + u];
    }

    if (s > 0) {
      // --- per-wave flag poll: lane i polls block i's flag (no contention RMW)
      const unsigned* fp = fl + ((lane & 31) << 4);
      const unsigned target = (unsigned)s;
      int spin = 0;
      for (;;) {
        unsigned v;
        asm volatile("global_load_dword %0, %1, off sc0 sc1\n\t"
                     "s_waitcnt vmcnt(0)"
                     : "=v"(v) : "v"(fp) : "memory");
        if (__all((int)(v >= target))) break;
        __builtin_amdgcn_s_sleep(1);
        if (++spin > (1 << 15)) break;  // failsafe: terminate > hang
      }
      // --- coherent load of h[t-1] slot (16KB, coalesced dwordx4)
      const float* rp = rg + ((s - 1) & 3) * 4096 + 8 * tid;
      float4 h0, h1;
      asm volatile("global_load_dwordx4 %0, %2, off sc0 sc1\n\t"
                   "global_load_dwordx4 %1, %2, off offset:16 sc0 sc1\n\t"
                   "s_waitcnt vmcnt(0)"
                   : "=&v"(h0), "=&v"(h1) : "v"(rp) : "memory");
      // transpose [u][b] -> hbuf[b][k=u]
      const int tu = tid >> 1, tb0 = (tid & 1) * 8;
      hbuf[(tb0 + 0) * 260 + tu] = h0.x;
      hbuf[(tb0 + 1) * 260 + tu] = h0.y;
      hbuf[(tb0 + 2) * 260 + tu] = h0.z;
      hbuf[(tb0 + 3) * 260 + tu] = h0.w;
      hbuf[(tb0 + 4) * 260 + tu] = h1.x;
      hbuf[(tb0 + 5) * 260 + tu] = h1.y;
      hbuf[(tb0 + 6) * 260 + tu] = h1.z;
      hbuf[(tb0 + 7) * 260 + tu] = h1.w;
    }
    __syncthreads();

    // --- dot: pj[i][j] = sum over 32 k of h[2bg+i][k] * Whh[k][4cg+j]
    float pj[2][4] = {};
#pragma unroll
    for (int i = 0; i < 2; ++i) {
      const float* hrow = &hbuf[(2 * bg + i) * 260];
#pragma unroll
      for (int m = 0; m < 8; ++m) {
        const float4 hv = *(const float4*)&hrow[4 * (kc + 8 * m)];
#pragma unroll
        for (int j = 0; j < 4; ++j) {
          pj[i][j] += hv.x * wf[j][m].x;
          pj[i][j] += hv.y * wf[j][m].y;
          pj[i][j] += hv.z * wf[j][m].z;
          pj[i][j] += hv.w * wf[j][m].w;
        }
      }
    }
#pragma unroll
    for (int i = 0; i < 2; ++i)
#pragma unroll
      for (int j = 0; j < 4; ++j)
        pbuf[(2 * bg + i) * 260 + (4 * cg + j) * 8 + kc] = pj[i][j];
    // pbuf producer wave == consumer wave (cg == uu) -> no __syncthreads needed.

    if (is_c) {
      float z[4];
#pragma unroll
      for (int j = 0; j < 4; ++j) {
        const float4 q0 = *(const float4*)&pbuf[b * 260 + (4 * uu + j) * 8];
        const float4 q1 = *(const float4*)&pbuf[b * 260 + (4 * uu + j) * 8 + 4];
        z[j] = ((q0.x + q0.y) + (q0.z + q0.w)) +
               ((q1.x + q1.y) + (q1.z + q1.w)) + xw4[j];
      }
      const float c2 = sigf(z[1]) * creg + sigf(z[0]) * tanhf(z[2]);
      const float h2 = sigf(z[3]) * tanhf(c2);
      creg = c2;
      // full-line uncached ring store (wave w covers u=g*8+w, b=0..15 = 64B)
      float* rp = rg + (s & 3) * 4096 + u * 16 + b;
      asm volatile("global_store_dword %0, %1, off sc0 sc1"
                   :: "v"(rp), "v"(h2) : "memory");
      hout[((b << 10) + t) * 256 + u] = h2;  // cached; read by later dispatches
    }
    // Drain own stores, then block-wide publish.
    asm volatile("s_waitcnt vmcnt(0)" ::: "memory");
    __syncthreads();
    if (tid == 0) {
      unsigned* fp = fl + g * 16;
      const unsigned v = (unsigned)(s + 1);
      asm volatile("global_store_dword %0, %1, off sc0 sc1"
                   :: "v"(fp), "v"(v) : "memory");
    }
  }
}

// ---------------- Decision pass (off the sequential critical path) ----------
__global__ __launch_bounds__(256)
void decide_k(const float* __restrict__ decH, const float* __restrict__ b12,
              const float* __restrict__ b3, const float* __restrict__ W4,
              const float* __restrict__ vt1, const float* __restrict__ vt2,
              const float* __restrict__ cemb, float* __restrict__ out)
{
  const int b = blockIdx.x, tid = threadIdx.x;
  __shared__ float v1s[256], add3[256], hrow[256], redv[256];
  __shared__ int   redi[256];
  __shared__ float s_out2;
  __shared__ int   s_r;
  v1s[tid] = vt1[tid];
  int bond = 0, last = 0;
  for (int iter = 0; iter < 1024; ++iter) {
    const int t = bond;
    hrow[tid] = decH[((b << 10) + t) * 256 + tid];
    redv[tid] = cemb[(t - last) * 256 + tid] * vt2[tid];
    __syncthreads();
    for (int off = 128; off; off >>= 1) {
      if (tid < off) redv[tid] += redv[tid + off];
      __syncthreads();
    }
    if (tid == 0) s_out2 = redv[0];
    __syncthreads();
    float a = 0.f;
#pragma unroll 4
    for (int k = 0; k < 256; ++k) a += hrow[k] * W4[k * 256 + tid];
    add3[tid] = a + b3[((b << 10) + t) * 256 + tid];
    __syncthreads();
    const float out2 = s_out2;
    float best = -INFINITY; int bestj = 0x7fffffff;
    for (int j = t + tid; j < 1024; j += 256) {
      const float* row = &b12[((b << 10) + j) * 256];
      float sacc = 0.f;
      for (int n = 0; n < 256; n += 4) {
        const float4 rv = *(const float4*)&row[n];
        sacc += tanhf(rv.x + add3[n + 0]) * v1s[n + 0];
        sacc += tanhf(rv.y + add3[n + 1]) * v1s[n + 1];
        sacc += tanhf(rv.z + add3[n + 2]) * v1s[n + 2];
        sacc += tanhf(rv.w + add3[n + 3]) * v1s[n + 3];
      }
      const float logit = sacc + out2;
      if (logit > best || (logit == best && j < bestj)) { best = logit; bestj = j; }
    }
    redv[tid] = best; redi[tid] = bestj;
    __syncthreads();
    for (int off = 128; off; off >>= 1) {
      if (tid < off) {
        const float v2 = redv[tid + off]; const int j2 = redi[tid + off];
        if (v2 > redv[tid] || (v2 == redv[tid] && j2 < redi[tid])) {
          redv[tid] = v2; redi[tid] = j2;
        }
      }
      __syncthreads();
    }
    if (tid == 0) { s_r = redi[0]; out[redi[0] * 16 + b] = 1.0f; }
    __syncthreads();
    const int r = s_r;
    if (r == t) break;
    last = t; bond = r;
    __syncthreads();
  }
}

// ---------------------------------------------------------------------------
extern "C" void kernel_launch(void* const* d_in, const int* in_sizes, int n_in,
                              void* d_out, int out_size, void* d_ws, size_t ws_size,
                              hipStream_t stream)
{
  const float* x     = (const float*)d_in[0];
  const float* Wih_f = (const float*)d_in[1];
  const float* Whh_f = (const float*)d_in[2];
  const float* b_f   = (const float*)d_in[3];
  const float* Wih_b = (const float*)d_in[4];
  const float* Whh_b = (const float*)d_in[5];
  const float* b_b   = (const float*)d_in[6];
  const float* dWih  = (const float*)d_in[7];
  const float* dWhh  = (const float*)d_in[8];
  const float* db    = (const float*)d_in[9];
  const float* W1    = (const float*)d_in[10];
  const float* W2    = (const float*)d_in[11];
  const float* W3    = (const float*)d_in[12];
  const float* W4    = (const float*)d_in[13];
  const float* vt1   = (const float*)d_in[14];
  const float* vt2   = (const float*)d_in[15];
  const float* cemb  = (const float*)d_in[16];
  float* out = (float*)d_out;

  char* ws = (char*)d_ws;
  float*    xWf   = (float*)(ws);                           // 64 MB (reused as decIn)
  float*    xWb   = (float*)(ws + (size_t)(64u << 20));     // 64 MB (reused as decH)
  float*    hn    = (float*)(ws + (size_t)(128u << 20));    // 16 MB
  float*    hb    = (float*)(ws + (size_t)(144u << 20));    // 16 MB
  float*    b12   = (float*)(ws + (size_t)(160u << 20));    // 16 MB
  float*    b3    = (float*)(ws + (size_t)(176u << 20));    // 16 MB
  float*    ring  = (float*)(ws + (size_t)(192u << 20));    // 3 dirs x 4 x 16KB
  unsigned* flags = (unsigned*)(ws + (size_t)(193u << 20)); // 3 x 2KB
  float* decIn = xWf;
  float* decH  = xWb;

  hipMemsetAsync(flags, 0, 3 * 512 * sizeof(unsigned), stream);
  hipMemsetAsync(out, 0, (size_t)out_size * sizeof(float), stream);

  const dim3 blk(256);
  gemm_k<0><<<dim3(16, 256), blk, 0, stream>>>(x, nullptr, Wih_f, b_f, xWf, 16384, 1024, 256, 0);
  gemm_k<0><<<dim3(16, 256), blk, 0, stream>>>(x, nullptr, Wih_b, b_b, xWb, 16384, 1024, 256, 0);
  gemm_k<0><<<dim3(4, 256),  blk, 0, stream>>>(x, nullptr, W2, nullptr, b12, 16384, 256, 256, 0);
  gemm_k<0><<<dim3(4, 256),  blk, 0, stream>>>(x, nullptr, W3, nullptr, b3,  16384, 256, 256, 0);
  // Encoder: 2 dirs x 32 blocks
  lstm_seq<<<64, 512, 0, stream>>>(xWf, xWb, Whh_f, Whh_b, hn, hb, nullptr,
                                   ring, flags, 1);
  gemm_k<1><<<dim3(16, 256), blk, 0, stream>>>(x, hn, dWih, db, decIn, 16384, 1024, 512, 0);
  gemm_k<2><<<dim3(4, 256),  blk, 0, stream>>>(hn, hb, W1, nullptr, b12, 16384, 256, 512, 1);
  // Decoder: 32 blocks, c0 = hn[:,1023,:]
  lstm_seq<<<32, 512, 0, stream>>>(decIn, nullptr, dWhh, nullptr, decH, nullptr, hn,
                                   ring + 2 * 4 * 4096, flags + 2 * 512, 0);
  decide_k<<<16, 256, 0, stream>>>(decH, b12, b3, W4, vt1, vt2, cemb, out);
}

// Round 4
// 6833.887 us; speedup vs baseline: 2.3122x; 1.1750x over previous
//
#include <hip/hip_runtime.h>
#include <math.h>

// ---------------------------------------------------------------------------
// PointerNetwork: biLSTM encoder + sequential pointer decoder (all fp32).
// Recurrences: 32 blocks/chain, Whh slices in VGPRs. Cross-block h exchange
// via a 1024-slot (never-reused) ring polled DIRECTLY with uncached loads:
// the 0xAA poison is the "not ready" sentinel, so the successful poll load
// IS the data load (no flags, no producer drain, one L3 hop on the path).
// ---------------------------------------------------------------------------

__device__ __forceinline__ float sigf(float x) { return 1.0f / (1.0f + expf(-x)); }

// ---------------- GEMM: C[M,N] = gather(A)[M,K] @ B[K,N] (+bias) (+accum) ---
template<int SRC>
__global__ __launch_bounds__(256)
void gemm_k(const float* __restrict__ A, const float* __restrict__ A2,
            const float* __restrict__ B, const float* __restrict__ bias,
            float* __restrict__ C, int M, int N, int K, int accum)
{
  __shared__ float As[16][68];
  __shared__ float Bs[16][64];
  const int tid = threadIdx.x;
  const int m0 = blockIdx.y * 64;
  const int n0 = blockIdx.x * 64;
  const int am = tid >> 2, akq = tid & 3;
  const int bkk = tid >> 4, bnq = tid & 15;
  const int tx = tid & 15, ty = tid >> 4;
  float acc[4][4] = {};
  for (int k0 = 0; k0 < K; k0 += 16) {
    float4 av;
    const int ar = m0 + am;
    const int ak = k0 + 4 * akq;
    if (SRC == 0) {
      av = *(const float4*)&A[ar * K + ak];
    } else if (SRC == 1) {
      const int bb = ar >> 10, t = ar & 1023;
      if (t == 0) { av = make_float4(0.f, 0.f, 0.f, 0.f); }
      else {
        const int src = ((bb << 10) + (t - 1)) * 256;
        av = (ak < 256) ? *(const float4*)&A[src + ak]
                        : *(const float4*)&A2[src + (ak - 256)];
      }
    } else {
      const int src = ar * 256;
      av = (ak < 256) ? *(const float4*)&A[src + ak]
                      : *(const float4*)&A2[src + (ak - 256)];
    }
    const float4 bv = *(const float4*)&B[(k0 + bkk) * N + n0 + 4 * bnq];
    As[4 * akq + 0][am] = av.x;
    As[4 * akq + 1][am] = av.y;
    As[4 * akq + 2][am] = av.z;
    As[4 * akq + 3][am] = av.w;
    *(float4*)&Bs[bkk][4 * bnq] = bv;
    __syncthreads();
#pragma unroll
    for (int kk = 0; kk < 16; ++kk) {
      const float4 a = *(const float4*)&As[kk][4 * ty];
      const float4 b = *(const float4*)&Bs[kk][4 * tx];
      acc[0][0] += a.x * b.x; acc[0][1] += a.x * b.y; acc[0][2] += a.x * b.z; acc[0][3] += a.x * b.w;
      acc[1][0] += a.y * b.x; acc[1][1] += a.y * b.y; acc[1][2] += a.y * b.z; acc[1][3] += a.y * b.w;
      acc[2][0] += a.z * b.x; acc[2][1] += a.z * b.y; acc[2][2] += a.z * b.z; acc[2][3] += a.z * b.w;
      acc[3][0] += a.w * b.x; acc[3][1] += a.w * b.y; acc[3][2] += a.w * b.z; acc[3][3] += a.w * b.w;
    }
    __syncthreads();
  }
  const float4 bsv = bias ? *(const float4*)&bias[n0 + 4 * tx] : make_float4(0.f, 0.f, 0.f, 0.f);
#pragma unroll
  for (int i = 0; i < 4; ++i) {
    float* crow = &C[(m0 + 4 * ty + i) * N + n0 + 4 * tx];
    float4 old = accum ? *(const float4*)crow : make_float4(0.f, 0.f, 0.f, 0.f);
    float4 r;
    r.x = acc[i][0] + old.x + bsv.x;
    r.y = acc[i][1] + old.y + bsv.y;
    r.z = acc[i][2] + old.z + bsv.z;
    r.w = acc[i][3] + old.w + bsv.w;
    *(float4*)crow = r;
  }
}

// ---------------- Sequential LSTM (data-as-flag polled ring) ----------------
// 512 threads. Compute role tid = cg*64+bg*8+kc (cg = wave id, owns units
// g*8+cg across 4 gates; kc = strided k-chunk; bg = batch pair).
// Output role tid = sc*16+b; gate0 lanes (sc=4w) finalize unit u=g*8+w.
// Ring: [1024 steps][256 u][16 b] floats, pre-poisoned 0xAA. Wave w stores
// one full 64B line per step; consumers poll their 32B until != sentinel.
__global__ __launch_bounds__(512, 1)
void lstm_seq(const float* __restrict__ xW0, const float* __restrict__ xW1,
              const float* __restrict__ Wr0, const float* __restrict__ Wr1,
              float* __restrict__ hout0, float* __restrict__ hout1,
              const float* __restrict__ cinit,
              float* __restrict__ ring,      // per dir: 1024*4096 floats
              int rev1)
{
  const int dir = blockIdx.x >> 5;
  const int g   = blockIdx.x & 31;
  const float* xW = dir ? xW1 : xW0;
  const float* Wr = dir ? Wr1 : Wr0;
  float* hout     = dir ? hout1 : hout0;
  float* rg       = ring + (size_t)dir * 1024 * 4096;

  const int tid  = threadIdx.x;
  // compute role
  const int kc = tid & 7;
  const int bg = (tid >> 3) & 7;
  const int cg = tid >> 6;            // == wave id
  // output role
  const int b    = tid & 15;
  const int sc   = tid >> 4;
  const int gate = sc & 3;
  const int uu   = sc >> 2;           // == wave id for gate0 lanes
  const int u    = g * 8 + uu;
  const bool is_c = (gate == 0);
  const unsigned SENT = 0xAAAAAAAAu;

  __shared__ float hbuf[16 * 260];    // h[b][k]
  __shared__ float pbuf[16 * 260];    // partials [b][c*8+kc] (wave-private use)

  // Register weight tile: cols (j<<8)+g*8+cg, k groups kc+8m.
  float4 wf[4][8];
#pragma unroll
  for (int j = 0; j < 4; ++j) {
    const int col = (j << 8) + g * 8 + cg;
#pragma unroll
    for (int m = 0; m < 8; ++m) {
      const int k0 = 4 * (kc + 8 * m);
      wf[j][m].x = Wr[(k0 + 0) * 1024 + col];
      wf[j][m].y = Wr[(k0 + 1) * 1024 + col];
      wf[j][m].z = Wr[(k0 + 2) * 1024 + col];
      wf[j][m].w = Wr[(k0 + 3) * 1024 + col];
    }
  }
#pragma unroll
  for (int e = 0; e < 8; ++e) hbuf[b * 260 + 8 * sc + e] = 0.0f;

  float creg = 0.0f;
  if (cinit && is_c) creg = cinit[((b << 10) + 1023) * 256 + u];
  __syncthreads();

  for (int s = 0; s < 1024; ++s) {
    const int t = (dir & rev1) ? (1023 - s) : s;

    // Prefetch this step's xW (cached; consumed late).
    float xw4[4];
    if (is_c) {
      const int row = ((b << 10) + t) * 1024;
#pragma unroll
      for (int j = 0; j < 4; ++j) xw4[j] = xW[row + j * 256 + u];
    }

    if (s > 0) {
      // --- poll h[t-1] directly: the successful load IS the data.
      const float* rp = rg + (size_t)(s - 1) * 4096 + 8 * tid;
      float4 h0, h1;
      int spin = 0;
      for (;;) {
        asm volatile("global_load_dwordx4 %0, %2, off sc0 sc1\n\t"
                     "global_load_dwordx4 %1, %2, off offset:16 sc0 sc1\n\t"
                     "s_waitcnt vmcnt(0)"
                     : "=&v"(h0), "=&v"(h1) : "v"(rp) : "memory");
        const int bad = (__float_as_uint(h0.x) == SENT) | (__float_as_uint(h0.y) == SENT) |
                        (__float_as_uint(h0.z) == SENT) | (__float_as_uint(h0.w) == SENT) |
                        (__float_as_uint(h1.x) == SENT) | (__float_as_uint(h1.y) == SENT) |
                        (__float_as_uint(h1.z) == SENT) | (__float_as_uint(h1.w) == SENT);
        if (!__any(bad)) break;
        if (++spin > (1 << 14)) break;  // failsafe: terminate > hang
      }
      // transpose [u][b] -> hbuf[b][k=u]
      const int tu = tid >> 1, tb0 = (tid & 1) * 8;
      hbuf[(tb0 + 0) * 260 + tu] = h0.x;
      hbuf[(tb0 + 1) * 260 + tu] = h0.y;
      hbuf[(tb0 + 2) * 260 + tu] = h0.z;
      hbuf[(tb0 + 3) * 260 + tu] = h0.w;
      hbuf[(tb0 + 4) * 260 + tu] = h1.x;
      hbuf[(tb0 + 5) * 260 + tu] = h1.y;
      hbuf[(tb0 + 6) * 260 + tu] = h1.z;
      hbuf[(tb0 + 7) * 260 + tu] = h1.w;
    }
    __syncthreads();

    // --- dot: pj[i][j] = sum over 32 k of h[2bg+i][k] * Whh[k][4cg+j]
    float pj[2][4] = {};
#pragma unroll
    for (int i = 0; i < 2; ++i) {
      const float* hrow = &hbuf[(2 * bg + i) * 260];
#pragma unroll
      for (int m = 0; m < 8; ++m) {
        const float4 hv = *(const float4*)&hrow[4 * (kc + 8 * m)];
#pragma unroll
        for (int j = 0; j < 4; ++j) {
          pj[i][j] += hv.x * wf[j][m].x;
          pj[i][j] += hv.y * wf[j][m].y;
          pj[i][j] += hv.z * wf[j][m].z;
          pj[i][j] += hv.w * wf[j][m].w;
        }
      }
    }
#pragma unroll
    for (int i = 0; i < 2; ++i)
#pragma unroll
      for (int j = 0; j < 4; ++j)
        pbuf[(2 * bg + i) * 260 + (4 * cg + j) * 8 + kc] = pj[i][j];
    // pbuf producer wave == consumer wave (cg == uu) -> no __syncthreads needed.

    if (is_c) {
      float z[4];
#pragma unroll
      for (int j = 0; j < 4; ++j) {
        const float4 q0 = *(const float4*)&pbuf[b * 260 + (4 * uu + j) * 8];
        const float4 q1 = *(const float4*)&pbuf[b * 260 + (4 * uu + j) * 8 + 4];
        z[j] = ((q0.x + q0.y) + (q0.z + q0.w)) +
               ((q1.x + q1.y) + (q1.z + q1.w)) + xw4[j];
      }
      const float c2 = sigf(z[1]) * creg + sigf(z[0]) * tanhf(z[2]);
      const float h2 = sigf(z[3]) * tanhf(c2);
      creg = c2;
      // Publish: one full 64B uncached line per wave. No drain, no flag —
      // the data itself is the readiness signal.
      float* rp = rg + (size_t)s * 4096 + u * 16 + b;
      asm volatile("global_store_dword %0, %1, off sc0 sc1"
                   :: "v"(rp), "v"(h2) : "memory");
      hout[((b << 10) + t) * 256 + u] = h2;  // cached; read by later dispatches
    }
    __syncthreads();  // protect hbuf (read by MAC) before next transpose write
  }
}

// ---------------- Decision pass (off the sequential critical path) ----------
__global__ __launch_bounds__(256)
void decide_k(const float* __restrict__ decH, const float* __restrict__ b12,
              const float* __restrict__ b3, const float* __restrict__ W4,
              const float* __restrict__ vt1, const float* __restrict__ vt2,
              const float* __restrict__ cemb, float* __restrict__ out)
{
  const int b = blockIdx.x, tid = threadIdx.x;
  __shared__ float v1s[256], add3[256], hrow[256], redv[256];
  __shared__ int   redi[256];
  __shared__ float s_out2;
  __shared__ int   s_r;
  v1s[tid] = vt1[tid];
  int bond = 0, last = 0;
  for (int iter = 0; iter < 1024; ++iter) {
    const int t = bond;
    hrow[tid] = decH[((b << 10) + t) * 256 + tid];
    redv[tid] = cemb[(t - last) * 256 + tid] * vt2[tid];
    __syncthreads();
    for (int off = 128; off; off >>= 1) {
      if (tid < off) redv[tid] += redv[tid + off];
      __syncthreads();
    }
    if (tid == 0) s_out2 = redv[0];
    __syncthreads();
    float a = 0.f;
#pragma unroll 4
    for (int k = 0; k < 256; ++k) a += hrow[k] * W4[k * 256 + tid];
    add3[tid] = a + b3[((b << 10) + t) * 256 + tid];
    __syncthreads();
    const float out2 = s_out2;
    float best = -INFINITY; int bestj = 0x7fffffff;
    for (int j = t + tid; j < 1024; j += 256) {
      const float* row = &b12[((b << 10) + j) * 256];
      float sacc = 0.f;
      for (int n = 0; n < 256; n += 4) {
        const float4 rv = *(const float4*)&row[n];
        sacc += tanhf(rv.x + add3[n + 0]) * v1s[n + 0];
        sacc += tanhf(rv.y + add3[n + 1]) * v1s[n + 1];
        sacc += tanhf(rv.z + add3[n + 2]) * v1s[n + 2];
        sacc += tanhf(rv.w + add3[n + 3]) * v1s[n + 3];
      }
      const float logit = sacc + out2;
      if (logit > best || (logit == best && j < bestj)) { best = logit; bestj = j; }
    }
    redv[tid] = best; redi[tid] = bestj;
    __syncthreads();
    for (int off = 128; off; off >>= 1) {
      if (tid < off) {
        const float v2 = redv[tid + off]; const int j2 = redi[tid + off];
        if (v2 > redv[tid] || (v2 == redv[tid] && j2 < redi[tid])) {
          redv[tid] = v2; redi[tid] = j2;
        }
      }
      __syncthreads();
    }
    if (tid == 0) { s_r = redi[0]; out[redi[0] * 16 + b] = 1.0f; }
    __syncthreads();
    const int r = s_r;
    if (r == t) break;
    last = t; bond = r;
    __syncthreads();
  }
}

// ---------------------------------------------------------------------------
extern "C" void kernel_launch(void* const* d_in, const int* in_sizes, int n_in,
                              void* d_out, int out_size, void* d_ws, size_t ws_size,
                              hipStream_t stream)
{
  const float* x     = (const float*)d_in[0];
  const float* Wih_f = (const float*)d_in[1];
  const float* Whh_f = (const float*)d_in[2];
  const float* b_f   = (const float*)d_in[3];
  const float* Wih_b = (const float*)d_in[4];
  const float* Whh_b = (const float*)d_in[5];
  const float* b_b   = (const float*)d_in[6];
  const float* dWih  = (const float*)d_in[7];
  const float* dWhh  = (const float*)d_in[8];
  const float* db    = (const float*)d_in[9];
  const float* W1    = (const float*)d_in[10];
  const float* W2    = (const float*)d_in[11];
  const float* W3    = (const float*)d_in[12];
  const float* W4    = (const float*)d_in[13];
  const float* vt1   = (const float*)d_in[14];
  const float* vt2   = (const float*)d_in[15];
  const float* cemb  = (const float*)d_in[16];
  float* out = (float*)d_out;

  char* ws = (char*)d_ws;
  float* xWf  = (float*)(ws);                        // 64 MB (reused as decIn)
  float* xWb  = (float*)(ws + (size_t)(64u << 20));  // 64 MB (reused as decH)
  float* hn   = (float*)(ws + (size_t)(128u << 20)); // 16 MB
  float* hb   = (float*)(ws + (size_t)(144u << 20)); // 16 MB
  float* b12  = (float*)(ws + (size_t)(160u << 20)); // 16 MB
  float* b3   = (float*)(ws + (size_t)(176u << 20)); // 16 MB
  float* ring = (float*)(ws + (size_t)(192u << 20)); // 3 dirs x 16 MB
  float* decIn = xWf;
  float* decH  = xWb;

  // Poison the rings: 0xAAAAAAAA is the "not ready" sentinel.
  hipMemsetAsync(ring, 0xAA, (size_t)3 * 1024 * 4096 * sizeof(float), stream);
  hipMemsetAsync(out, 0, (size_t)out_size * sizeof(float), stream);

  const dim3 blk(256);
  gemm_k<0><<<dim3(16, 256), blk, 0, stream>>>(x, nullptr, Wih_f, b_f, xWf, 16384, 1024, 256, 0);
  gemm_k<0><<<dim3(16, 256), blk, 0, stream>>>(x, nullptr, Wih_b, b_b, xWb, 16384, 1024, 256, 0);
  gemm_k<0><<<dim3(4, 256),  blk, 0, stream>>>(x, nullptr, W2, nullptr, b12, 16384, 256, 256, 0);
  gemm_k<0><<<dim3(4, 256),  blk, 0, stream>>>(x, nullptr, W3, nullptr, b3,  16384, 256, 256, 0);
  // Encoder: 2 dirs x 32 blocks
  lstm_seq<<<64, 512, 0, stream>>>(xWf, xWb, Whh_f, Whh_b, hn, hb, nullptr, ring, 1);
  gemm_k<1><<<dim3(16, 256), blk, 0, stream>>>(x, hn, dWih, db, decIn, 16384, 1024, 512, 0);
  gemm_k<2><<<dim3(4, 256),  blk, 0, stream>>>(hn, hb, W1, nullptr, b12, 16384, 256, 512, 1);
  // Decoder: 32 blocks, c0 = hn[:,1023,:]
  lstm_seq<<<32, 512, 0, stream>>>(decIn, nullptr, dWhh, nullptr, decH, nullptr, hn,
                                   ring + (size_t)2 * 1024 * 4096, 0);
  decide_k<<<16, 256, 0, stream>>>(decH, b12, b3, W4, vt1, vt2, cemb, out);
}